// Round 11
// baseline (571.366 us; speedup 1.0000x reference)
//
#include <hip/hip_runtime.h>
#include <math.h>

typedef __bf16 v8bf __attribute__((ext_vector_type(8)));
typedef __bf16 v4bf __attribute__((ext_vector_type(4)));
typedef float  v16f __attribute__((ext_vector_type(16)));
typedef float  v4f  __attribute__((ext_vector_type(4)));

#define EPS_BN 1e-5f
#define Q_TOTAL 16384
#define N_MEM   262144
#define SLICES  64
#define SLICE_LEN (N_MEM / SLICES)   /* 4096 */
#define CHUNK   128
#define NCHUNKS (SLICE_LEN / CHUNK)  /* 32 */

// async global->LDS, 16B/lane. LDS dest is wave-uniform base + lane*16, so
// the bank swizzle must be folded into the GLOBAL source addresses.
__device__ __forceinline__ void gload_lds16(const void* g, void* l) {
    __builtin_amdgcn_global_load_lds(
        (const __attribute__((address_space(1))) void*)g,
        (__attribute__((address_space(3))) void*)l, 16, 0, 0);
}

// ---------------------------------------------------------------------------
// conv0: [256,1,64,64] -> [256,16,32,32], 3x3 s2 p1 + BN + ReLU
__global__ void conv0_kernel(const float* __restrict__ x,
                             const float* __restrict__ w, const float* __restrict__ bias,
                             const float* __restrict__ gamma, const float* __restrict__ beta,
                             const float* __restrict__ mean, const float* __restrict__ var,
                             float* __restrict__ out) {
    int idx = blockIdx.x * 256 + threadIdx.x;
    int xo = idx & 31, yo = (idx >> 5) & 31, c = (idx >> 10) & 15, b = idx >> 14;
    const float* xp = x + (size_t)b * 4096;
    const float* wc = w + c * 9;
    float acc = 0.f;
#pragma unroll
    for (int dy = 0; dy < 3; ++dy) {
        int iy = 2 * yo + dy - 1;
        if (iy < 0) continue;
#pragma unroll
        for (int dx = 0; dx < 3; ++dx) {
            int ix = 2 * xo + dx - 1;
            if (ix < 0) continue;
            acc += wc[dy * 3 + dx] * xp[iy * 64 + ix];
        }
    }
    acc += bias[c];
    float sc = gamma[c] * rsqrtf(var[c] + EPS_BN);
    float v  = (acc - mean[c]) * sc + beta[c];
    out[idx] = fmaxf(v, 0.f);
}

// ---------------------------------------------------------------------------
// conv1 v3: [256,16,32,32] -> [256,32,16,16]. ONE block per image (was 4):
// stage the 64 KB image once (v2 staged it 4x -> 67 MB global reads for a
// 16.8 MB tensor). 512 threads: thread (px = t&255, half = t>>8) computes 16
// output channels for its pixel. half is wave-uniform -> weight reads stay
// on the s_load scalar path. Writes fully coalesced (consecutive px).
__global__ void conv1_kernel(const float* __restrict__ in,
                             const float* __restrict__ w, const float* __restrict__ bias,
                             const float* __restrict__ gamma, const float* __restrict__ beta,
                             const float* __restrict__ mean, const float* __restrict__ var,
                             float* __restrict__ out) {
    __shared__ float in_s[16384];            // 64 KB: [16 ci][32 y][32 x]
    __shared__ float sc_s[32], sh_s[32];
    int b = blockIdx.x, t = threadIdx.x;     // 256 blocks, 512 threads
    const float4* ip4 = (const float4*)(in + (size_t)b * 16384);
    float4* is4 = (float4*)in_s;
    for (int i = t; i < 4096; i += 512) is4[i] = ip4[i];
    if (t < 32) {
        float sc = gamma[t] * rsqrtf(var[t] + EPS_BN);
        sc_s[t] = sc;
        sh_s[t] = (bias[t] - mean[t]) * sc + beta[t];
    }
    __syncthreads();
    int px = t & 255, half = t >> 8;         // half wave-uniform
    int xo = px & 15, yo = px >> 4;
    const float* wg = w + half * 2304;       // w[32][16][9]; ch = half*16 + c
    float acc[16];
#pragma unroll
    for (int c = 0; c < 16; ++c) acc[c] = 0.f;
    int iy0 = 2 * yo - 1, ix0 = 2 * xo - 1;
    for (int ci = 0; ci < 16; ++ci) {
        const float* base = in_s + ci * 1024;
        float r[9];
#pragma unroll
        for (int dy = 0; dy < 3; ++dy) {
            int iy = iy0 + dy;
            int iyc = iy < 0 ? 0 : iy;
#pragma unroll
            for (int dx = 0; dx < 3; ++dx) {
                int ix = ix0 + dx;
                int ixc = ix < 0 ? 0 : ix;
                float v = base[iyc * 32 + ixc];
                r[dy * 3 + dx] = (iy >= 0 && ix >= 0) ? v : 0.f;
            }
        }
#pragma unroll
        for (int c = 0; c < 16; ++c) {
            const float* wp = wg + (c * 16 + ci) * 9;   // wave-uniform addr
#pragma unroll
            for (int k = 0; k < 9; ++k) acc[c] = fmaf(wp[k], r[k], acc[c]);
        }
    }
#pragma unroll
    for (int c = 0; c < 16; ++c) {
        int ch = half * 16 + c;
        float v = fmaf(acc[c], sc_s[ch], sh_s[ch]);
        out[((size_t)(b * 32 + ch) * 16 + yo) * 16 + xo] = fmaxf(v, 0.f);
    }
}

// ---------------------------------------------------------------------------
// conv2q: conv2 + qnorm FUSED, one block per image. 512 threads.
// Phase 1 (conv): thread (px = t&63, oct = t>>6) computes 8 channels; oct is
// wave-uniform -> s_load weights. BN+ReLU -> out_s[px][ch] padded [64][65]
// (stride 65: writes/reads 2-way max = free). Phase 2 (qnorm): thread
// (p2 = t>>3, dg = t&7) L2-normalizes its pixel's 8 dims via 3-step 8-lane
// shfl reduce, writes bf16 q + qsq from bf16-rounded values. Kills the y2
// round-trip (4.2 MB write + read) and one launch. Also inits mind2.
__global__ void conv2q_kernel(const float* __restrict__ in,
                              const float* __restrict__ w, const float* __restrict__ bias,
                              const float* __restrict__ gamma, const float* __restrict__ beta,
                              const float* __restrict__ mean, const float* __restrict__ var,
                              __bf16* __restrict__ q, float* __restrict__ qsq,
                              unsigned int* __restrict__ mind2) {
    __shared__ float in_s[8192];             // 32 KB: [32 ci][16 y][16 x]
    __shared__ float out_s[64 * 65];         // 16.6 KB, padded stride 65
    __shared__ float sc_s[64], sh_s[64];
    int b = blockIdx.x, t = threadIdx.x;     // 256 blocks, 512 threads
    if (t < 64) mind2[b * 64 + t] = 0x7f800000u;   // +inf init for dist
    const float4* ip4 = (const float4*)(in + (size_t)b * 8192);
    float4* is4 = (float4*)in_s;
    for (int i = t; i < 2048; i += 512) is4[i] = ip4[i];
    if (t < 64) {
        float sc = gamma[t] * rsqrtf(var[t] + EPS_BN);
        sc_s[t] = sc;
        sh_s[t] = (bias[t] - mean[t]) * sc + beta[t];
    }
    __syncthreads();
    int px = t & 63, oct = t >> 6;           // oct wave-uniform
    int xo = px & 7, yo = px >> 3;
    const float* wg = w + oct * 2304;        // w[64][32][9]; ch = oct*8 + c
    float acc[8];
#pragma unroll
    for (int c = 0; c < 8; ++c) acc[c] = 0.f;
    int iy0 = 2 * yo - 1, ix0 = 2 * xo - 1;
    for (int ci = 0; ci < 32; ++ci) {
        const float* base = in_s + ci * 256;
        float r[9];
#pragma unroll
        for (int dy = 0; dy < 3; ++dy) {
            int iy = iy0 + dy;
            int iyc = iy < 0 ? 0 : iy;
#pragma unroll
            for (int dx = 0; dx < 3; ++dx) {
                int ix = ix0 + dx;
                int ixc = ix < 0 ? 0 : ix;
                float v = base[iyc * 16 + ixc];
                r[dy * 3 + dx] = (iy >= 0 && ix >= 0) ? v : 0.f;
            }
        }
#pragma unroll
        for (int c = 0; c < 8; ++c) {
            const float* wp = wg + (c * 32 + ci) * 9;   // wave-uniform addr
#pragma unroll
            for (int k = 0; k < 9; ++k) acc[c] = fmaf(wp[k], r[k], acc[c]);
        }
    }
#pragma unroll
    for (int c = 0; c < 8; ++c) {
        int ch = oct * 8 + c;
        float v = fmaf(acc[c], sc_s[ch], sh_s[ch]);
        out_s[px * 65 + ch] = fmaxf(v, 0.f);
    }
    __syncthreads();
    // qnorm from out_s
    int p2 = t >> 3, dg = t & 7;             // 8 lanes per pixel (same wave)
    float vv[8];
    float ss = 0.f;
#pragma unroll
    for (int i = 0; i < 8; ++i) {
        vv[i] = out_s[p2 * 65 + dg * 8 + i];
        ss += vv[i] * vv[i];
    }
    ss += __shfl_xor(ss, 1, 64);
    ss += __shfl_xor(ss, 2, 64);
    ss += __shfl_xor(ss, 4, 64);
    float inv = 1.f / fmaxf(sqrtf(ss), 1e-12f);
    v8bf o;
    float q2 = 0.f;
#pragma unroll
    for (int i = 0; i < 8; ++i) {
        __bf16 bv = (__bf16)(vv[i] * inv);
        o[i] = bv;
        float fb = (float)bv;
        q2 += fb * fb;                       // qsq from bf16-rounded
    }
    q2 += __shfl_xor(q2, 1, 64);
    q2 += __shfl_xor(q2, 2, 64);
    q2 += __shfl_xor(q2, 4, 64);
    if (dg == 0) qsq[b * 64 + p2] = q2;
    *(v8bf*)(q + ((size_t)(b * 64 + p2)) * 64 + dg * 8) = o;
}

// ---------------------------------------------------------------------------
// mbnorm v2: 16 threads/row, float4 per thread, 4-step 16-lane reduction,
// vectorized 8B bf16 store. msq := 1 in dist (unit rows).
__global__ void mbnorm_kernel(const float* __restrict__ mb,
                              __bf16* __restrict__ mbbf) {
    int tid = blockIdx.x * 256 + threadIdx.x;
    int row = tid >> 4, sub = tid & 15;
    const float4 v = *(const float4*)(mb + (size_t)row * 64 + sub * 4);
    float ss = v.x * v.x + v.y * v.y + v.z * v.z + v.w * v.w;
#pragma unroll
    for (int o = 1; o < 16; o <<= 1) ss += __shfl_xor(ss, o, 64);
    float inv = 1.f / fmaxf(sqrtf(ss), 1e-12f);
    v4bf o;
    o[0] = (__bf16)(v.x * inv);
    o[1] = (__bf16)(v.y * inv);
    o[2] = (__bf16)(v.z * inv);
    o[3] = (__bf16)(v.w * inv);
    *(v4bf*)(mbbf + (size_t)row * 64 + sub * 4) = o;
}

// ---------------------------------------------------------------------------
// dist v18 = v14 VERBATIM (331.7-332.1us across R9/R10, MfmaUtil ~80% of the
// 264.9us 16x16-pipe floor — banked best. R3/R6/R7: more residency spills;
// R8: in-lane-fold alternative issues worse; R10 arithmetic: 32x32 MFMA needs
// either 2x LDS-read BW (>90% of 69 TB/s ceiling, 1 q-strip) or tmax[2][16]
// persistent regs (spill, 2 q-strips) — 16x16 is structurally correct).
__global__ __launch_bounds__(256, 4)
void dist_kernel(const __bf16* __restrict__ q, const float* __restrict__ qsq,
                 const __bf16* __restrict__ mb,
                 unsigned int* __restrict__ mind2) {
    __shared__ __align__(16) __bf16 Bs[2][CHUNK * 64];   // 2 x 16 KB
    const int t = threadIdx.x;
    const int wave = t >> 6, lane = t & 63;
    const int c16 = lane & 15;        // m-col within tile / q-row for A
    const int kblk = lane >> 4;       // 0..3: k-subblock
    const int mbase = blockIdx.x * 256 + wave * 64;
    const int slice = blockIdx.y;

    // A fragments: 4 strips x 2 ksteps (32 VGPR).
    v8bf a[4][2];
#pragma unroll
    for (int s = 0; s < 4; ++s)
#pragma unroll
        for (int ks = 0; ks < 2; ++ks)
            a[s][ks] = *(const v8bf*)(q + (size_t)(mbase + s * 16 + c16) * 64
                                        + ks * 32 + kblk * 8);

    float tmax[4][4];
#pragma unroll
    for (int s = 0; s < 4; ++s)
#pragma unroll
        for (int r = 0; r < 4; ++r) tmax[s][r] = -3.0e38f;

    v4f Z;                            // hoisted zero C-operand (4 regs)
#pragma unroll
    for (int r = 0; r < 4; ++r) Z[r] = 0.f;

    // staging: granule g=j*256+t -> row g>>3, slot (g&7)^(row&7); granule j
    // at LDS offset j*4096 (j*32 ≡ 0 mod 8 -> swizzle j-invariant).
    const int r0 = t >> 3, c0 = (t & 7) ^ (r0 & 7);
    const __bf16* gp = mb + (size_t)slice * SLICE_LEN * 64 + r0 * 64 + c0 * 8;
    const int wbase = wave * 1024;

    // prologue: chunk 0 -> buf 0 (4 granules of 4KB)
#pragma unroll
    for (int j = 0; j < 4; ++j) {
        gload_lds16(gp, (char*)Bs[0] + j * 4096 + wbase);
        gp += 2048;
    }

    // ds_read offsets: data k-slot κ = kblk + 4*ks lives at physical slot
    // κ ^ (row&7); row = c16 -> byte = c16*128 + ((κ ^ (lane&7))<<4).
    const int rowb = c16 * 128;
    int offk[2];
#pragma unroll
    for (int ks = 0; ks < 2; ++ks) offk[ks] = (((kblk + 4 * ks) ^ (lane & 7)) << 4);

    auto step = [&](const char* bp, char* pdst, bool more) {
        __syncthreads();              // drains staging (vmcnt0) + sync
        if (more) {
#pragma unroll
            for (int j = 0; j < 4; ++j) {
                gload_lds16(gp, pdst + j * 4096 + wbase);
                gp += 2048;
            }
        }
        const char* tp = bp + rowb;
        v8bf be[2], bo[2];
#pragma unroll
        for (int ks = 0; ks < 2; ++ks) {
            be[ks] = *(const v8bf*)(tp + offk[ks]);           // m-tile 0
            bo[ks] = *(const v8bf*)(tp + 2048 + offk[ks]);    // m-tile 1
        }
#pragma unroll 1
        for (int p = 0; p < 4; ++p) {
            v4f Ae[4], Ao[4];
            // ks0: 8 independent chain heads
#pragma unroll
            for (int s = 0; s < 4; ++s)
                Ae[s] = __builtin_amdgcn_mfma_f32_16x16x32_bf16(a[s][0], be[0], Z, 0, 0, 0);
#pragma unroll
            for (int s = 0; s < 4; ++s)
                Ao[s] = __builtin_amdgcn_mfma_f32_16x16x32_bf16(a[s][0], bo[0], Z, 0, 0, 0);
            // ks1: finish the chains (dep gap = 8 issues)
#pragma unroll
            for (int s = 0; s < 4; ++s)
                Ae[s] = __builtin_amdgcn_mfma_f32_16x16x32_bf16(a[s][1], be[1], Ae[s], 0, 0, 0);
#pragma unroll
            for (int s = 0; s < 4; ++s)
                Ao[s] = __builtin_amdgcn_mfma_f32_16x16x32_bf16(a[s][1], bo[1], Ao[s], 0, 0, 0);
            // reload be/bo in place for the next pair (WAR safe: in-order issue)
            if (p < 3) {
                const char* tn = tp + (p + 1) * 4096;
#pragma unroll
                for (int ks = 0; ks < 2; ++ks) {
                    be[ks] = *(const v8bf*)(tn + offk[ks]);
                    bo[ks] = *(const v8bf*)(tn + 2048 + offk[ks]);
                }
            }
            // fold both m-tiles: fmax(fmax(.,.),.) -> v_max3_f32
#pragma unroll
            for (int s = 0; s < 4; ++s)
#pragma unroll
                for (int r = 0; r < 4; ++r)
                    tmax[s][r] = fmaxf(fmaxf(Ae[s][r], Ao[s][r]), tmax[s][r]);
        }
    };

    for (int ch = 0; ch < NCHUNKS; ch += 2) {
        step((const char*)Bs[0], (char*)Bs[1], ch + 1 < NCHUNKS);
        step((const char*)Bs[1], (char*)Bs[0], ch + 2 < NCHUNKS);
    }

    // cross-lane max over the 16 m-cols (lanes sharing lane>>4)
#pragma unroll
    for (int s = 0; s < 4; ++s)
#pragma unroll
        for (int r = 0; r < 4; ++r) {
            float v = tmax[s][r];
            v = fmaxf(v, __shfl_xor(v, 1, 64));
            v = fmaxf(v, __shfl_xor(v, 2, 64));
            v = fmaxf(v, __shfl_xor(v, 4, 64));
            v = fmaxf(v, __shfl_xor(v, 8, 64));
            tmax[s][r] = v;
        }
    if (c16 == 0) {
#pragma unroll
        for (int s = 0; s < 4; ++s)
#pragma unroll
            for (int r = 0; r < 4; ++r) {
                int m = mbase + s * 16 + kblk * 4 + r;  // C/D row map
                // d^2 = qsq + |m|^2 - 2 dot, |m|^2 := 1 (unit rows)
                float dd = fmaxf(qsq[m] + 1.0f - 2.0f * tmax[s][r], 0.f);
                atomicMin(mind2 + m, __float_as_uint(dd));
            }
    }
}

// finalize: out[b] = max_p sqrt(mind2[b*64+p])
__global__ void finalize_kernel(const unsigned int* __restrict__ mind2,
                                float* __restrict__ out) {
    int b = blockIdx.x, l = threadIdx.x;
    float v = __uint_as_float(mind2[b * 64 + l]);
    float d = sqrtf(fmaxf(v, 0.f));
#pragma unroll
    for (int o = 1; o < 64; o <<= 1) d = fmaxf(d, __shfl_xor(d, o, 64));
    if (l == 0) out[b] = d;
}

// ---------------------------------------------------------------------------
extern "C" void kernel_launch(void* const* d_in, const int* in_sizes, int n_in,
                              void* d_out, int out_size, void* d_ws, size_t ws_size,
                              hipStream_t stream) {
    (void)in_sizes; (void)n_in; (void)out_size; (void)ws_size;
    const float* x     = (const float*)d_in[0];
    const float* mbank = (const float*)d_in[1];
    const float* w0 = (const float*)d_in[2],  *b0 = (const float*)d_in[3];
    const float* g0 = (const float*)d_in[4],  *be0 = (const float*)d_in[5];
    const float* mn0 = (const float*)d_in[6], *vr0 = (const float*)d_in[7];
    const float* w1 = (const float*)d_in[8],  *b1 = (const float*)d_in[9];
    const float* g1 = (const float*)d_in[10], *be1 = (const float*)d_in[11];
    const float* mn1 = (const float*)d_in[12], *vr1 = (const float*)d_in[13];
    const float* w2 = (const float*)d_in[14], *b2 = (const float*)d_in[15];
    const float* g2 = (const float*)d_in[16], *be2 = (const float*)d_in[17];
    const float* mn2 = (const float*)d_in[18], *vr2 = (const float*)d_in[19];

    char* ws = (char*)d_ws;
    float*        y0    = (float*)(ws + 0);              // 16.78 MB
    float*        y1    = (float*)(ws + 16777216);       // 8.39 MB
    __bf16*       qbf   = (__bf16*)(ws + 29360128);      // 2.10 MB
    float*        qsq   = (float*)(ws + 31457280);       // 64 KB
    __bf16*       mbbf  = (__bf16*)(ws + 31522816);      // 33.55 MB
    unsigned int* mind2 = (unsigned int*)(ws + 66125824);// 64 KB

    conv0_kernel<<<16384, 256, 0, stream>>>(x, w0, b0, g0, be0, mn0, vr0, y0);
    conv1_kernel<<<256, 512, 0, stream>>>(y0, w1, b1, g1, be1, mn1, vr1, y1);
    conv2q_kernel<<<256, 512, 0, stream>>>(y1, w2, b2, g2, be2, mn2, vr2,
                                           qbf, qsq, mind2);
    mbnorm_kernel<<<16384, 256, 0, stream>>>(mbank, mbbf);
    dist_kernel<<<dim3(64, SLICES), 256, 0, stream>>>(qbf, qsq, mbbf, mind2);
    finalize_kernel<<<256, 64, 0, stream>>>(mind2, (float*)d_out);
}

// Round 12
// 564.953 us; speedup vs baseline: 1.0114x; 1.0114x over previous
//
#include <hip/hip_runtime.h>
#include <math.h>

typedef __bf16 v8bf __attribute__((ext_vector_type(8)));
typedef __bf16 v4bf __attribute__((ext_vector_type(4)));
typedef float  v16f __attribute__((ext_vector_type(16)));
typedef float  v4f  __attribute__((ext_vector_type(4)));

#define EPS_BN 1e-5f
#define Q_TOTAL 16384
#define N_MEM   262144
#define SLICES  64
#define SLICE_LEN (N_MEM / SLICES)   /* 4096 */
#define CHUNK   128
#define NCHUNKS (SLICE_LEN / CHUNK)  /* 32 */

// async global->LDS, 16B/lane. LDS dest is wave-uniform base + lane*16, so
// the bank swizzle must be folded into the GLOBAL source addresses.
__device__ __forceinline__ void gload_lds16(const void* g, void* l) {
    __builtin_amdgcn_global_load_lds(
        (const __attribute__((address_space(1))) void*)g,
        (__attribute__((address_space(3))) void*)l, 16, 0, 0);
}

// ---------------------------------------------------------------------------
// conv0: [256,1,64,64] -> [256,16,32,32], 3x3 s2 p1 + BN + ReLU
__global__ void conv0_kernel(const float* __restrict__ x,
                             const float* __restrict__ w, const float* __restrict__ bias,
                             const float* __restrict__ gamma, const float* __restrict__ beta,
                             const float* __restrict__ mean, const float* __restrict__ var,
                             float* __restrict__ out) {
    int idx = blockIdx.x * 256 + threadIdx.x;
    int xo = idx & 31, yo = (idx >> 5) & 31, c = (idx >> 10) & 15, b = idx >> 14;
    const float* xp = x + (size_t)b * 4096;
    const float* wc = w + c * 9;
    float acc = 0.f;
#pragma unroll
    for (int dy = 0; dy < 3; ++dy) {
        int iy = 2 * yo + dy - 1;
        if (iy < 0) continue;
#pragma unroll
        for (int dx = 0; dx < 3; ++dx) {
            int ix = 2 * xo + dx - 1;
            if (ix < 0) continue;
            acc += wc[dy * 3 + dx] * xp[iy * 64 + ix];
        }
    }
    acc += bias[c];
    float sc = gamma[c] * rsqrtf(var[c] + EPS_BN);
    float v  = (acc - mean[c]) * sc + beta[c];
    out[idx] = fmaxf(v, 0.f);
}

// ---------------------------------------------------------------------------
// conv1 v2 (R10 best): input staged in LDS (per-lane varying); WEIGHTS read
// directly from GLOBAL with wave-uniform addresses -> s_load scalar path.
// 4 blocks/image keeps 1024 blocks of parallelism (R11 proved 256x1-block
// regresses ~8us: width beats the L2-absorbed redundant reads).
__global__ void conv1_kernel(const float* __restrict__ in,
                             const float* __restrict__ w, const float* __restrict__ bias,
                             const float* __restrict__ gamma, const float* __restrict__ beta,
                             const float* __restrict__ mean, const float* __restrict__ var,
                             float* __restrict__ out) {
    __shared__ float in_s[16384];
    __shared__ float sc_s[8], sh_s[8];
    int b = blockIdx.x >> 2, cg = blockIdx.x & 3;
    int t = threadIdx.x;
    const float4* ip4 = (const float4*)(in + (size_t)b * 16384);
    float4* is4 = (float4*)in_s;
    for (int i = t; i < 4096; i += 256) is4[i] = ip4[i];
    if (t < 8) {
        int c = cg * 8 + t;
        float sc = gamma[c] * rsqrtf(var[c] + EPS_BN);
        sc_s[t] = sc;
        sh_s[t] = (bias[c] - mean[c]) * sc + beta[c];
    }
    __syncthreads();
    const float* wg = w + cg * 1152;          // uniform base -> s_load path
    int xo = t & 15, yo = t >> 4;
    float acc[8];
#pragma unroll
    for (int c = 0; c < 8; ++c) acc[c] = 0.f;
    int iy0 = 2 * yo - 1, ix0 = 2 * xo - 1;
    for (int ci = 0; ci < 16; ++ci) {
        const float* base = in_s + ci * 1024;
        float r[9];
#pragma unroll
        for (int dy = 0; dy < 3; ++dy) {
            int iy = iy0 + dy;
            int iyc = iy < 0 ? 0 : iy;
#pragma unroll
            for (int dx = 0; dx < 3; ++dx) {
                int ix = ix0 + dx;
                int ixc = ix < 0 ? 0 : ix;
                float v = base[iyc * 32 + ixc];
                r[dy * 3 + dx] = (iy >= 0 && ix >= 0) ? v : 0.f;
            }
        }
#pragma unroll
        for (int c = 0; c < 8; ++c) {
            const float* wp = wg + (c * 16 + ci) * 9;   // uniform address
#pragma unroll
            for (int k = 0; k < 9; ++k) acc[c] = fmaf(wp[k], r[k], acc[c]);
        }
    }
#pragma unroll
    for (int c = 0; c < 8; ++c) {
        float v = fmaf(acc[c], sc_s[c], sh_s[c]);
        out[((size_t)(b * 32 + cg * 8 + c) * 16 + yo) * 16 + xo] = fmaxf(v, 0.f);
    }
}

// ---------------------------------------------------------------------------
// conv2 v2 (R10 best): same weight de-LDS-ification (cs = t>>6 wave-uniform
// -> s_load). LDS 8 KB.
__global__ void conv2_kernel(const float* __restrict__ in,
                             const float* __restrict__ w, const float* __restrict__ bias,
                             const float* __restrict__ gamma, const float* __restrict__ beta,
                             const float* __restrict__ mean, const float* __restrict__ var,
                             float* __restrict__ out) {
    __shared__ float in_s[8192];
    __shared__ float sc_s[16], sh_s[16];
    int b = blockIdx.x >> 2, cg = blockIdx.x & 3;
    int t = threadIdx.x;
    const float4* ip4 = (const float4*)(in + (size_t)b * 8192);
    float4* is4 = (float4*)in_s;
    for (int i = t; i < 2048; i += 256) is4[i] = ip4[i];
    if (t < 16) {
        int c = cg * 16 + t;
        float sc = gamma[c] * rsqrtf(var[c] + EPS_BN);
        sc_s[t] = sc;
        sh_s[t] = (bias[c] - mean[c]) * sc + beta[c];
    }
    __syncthreads();
    const float* wg = w + cg * 4608;          // uniform base -> s_load path
    int xo = t & 7, yo = (t >> 3) & 7, cs = t >> 6;
    float acc[4];
#pragma unroll
    for (int l = 0; l < 4; ++l) acc[l] = 0.f;
    int iy0 = 2 * yo - 1, ix0 = 2 * xo - 1;
    for (int ci = 0; ci < 32; ++ci) {
        const float* base = in_s + ci * 256;
        float r[9];
#pragma unroll
        for (int dy = 0; dy < 3; ++dy) {
            int iy = iy0 + dy;
            int iyc = iy < 0 ? 0 : iy;
#pragma unroll
            for (int dx = 0; dx < 3; ++dx) {
                int ix = ix0 + dx;
                int ixc = ix < 0 ? 0 : ix;
                float v = base[iyc * 16 + ixc];
                r[dy * 3 + dx] = (iy >= 0 && ix >= 0) ? v : 0.f;
            }
        }
#pragma unroll
        for (int l = 0; l < 4; ++l) {
            const float* wp = wg + ((cs * 4 + l) * 32 + ci) * 9;  // wave-uniform
#pragma unroll
            for (int k = 0; k < 9; ++k) acc[l] = fmaf(wp[k], r[k], acc[l]);
        }
    }
#pragma unroll
    for (int l = 0; l < 4; ++l) {
        int c = cg * 16 + cs * 4 + l;
        float v = fmaf(acc[l], sc_s[cs * 4 + l], sh_s[cs * 4 + l]);
        out[((size_t)(b * 64 + c) * 8 + yo) * 8 + xo] = fmaxf(v, 0.f);
    }
}

// ---------------------------------------------------------------------------
// qnorm v2 (R9, kept): 256 threads, 4-lane quad per pixel, shfl_xor(1,2)
// quad-reduce, vectorized 2x16B bf16 stores. No LDS.
__global__ void qnorm_kernel(const float* __restrict__ y2,
                             __bf16* __restrict__ q, float* __restrict__ qsq,
                             unsigned int* __restrict__ mind2) {
    int b = blockIdx.x, t = threadIdx.x;          // 256 threads
    if (t < 64) mind2[b * 64 + t] = 0x7f800000u;  // +inf init
    int p = t >> 2, dg = t & 3;                   // pixel, 16-dim group
    const float* src = y2 + (size_t)b * 4096 + p; // [64 ch][64 px], stride 64
    float v[16];
    float ss = 0.f;
#pragma unroll
    for (int i = 0; i < 16; ++i) {
        v[i] = src[(dg * 16 + i) * 64];
        ss += v[i] * v[i];
    }
    ss += __shfl_xor(ss, 1, 64);                  // quad lanes share pixel p
    ss += __shfl_xor(ss, 2, 64);
    float inv = 1.f / fmaxf(sqrtf(ss), 1e-12f);
    v8bf o0, o1;
    float q2 = 0.f;
#pragma unroll
    for (int i = 0; i < 16; ++i) {
        __bf16 bv = (__bf16)(v[i] * inv);
        if (i < 8) o0[i] = bv; else o1[i - 8] = bv;
        float fb = (float)bv;
        q2 += fb * fb;                            // qsq from bf16-rounded
    }
    q2 += __shfl_xor(q2, 1, 64);
    q2 += __shfl_xor(q2, 2, 64);
    if (dg == 0) qsq[b * 64 + p] = q2;
    __bf16* dst = q + ((size_t)(b * 64 + p)) * 64 + dg * 16;
    *(v8bf*)dst = o0;
    *(v8bf*)(dst + 8) = o1;
}

// ---------------------------------------------------------------------------
// mbnorm v2: 16 threads/row, float4 per thread, 4-step 16-lane reduction,
// vectorized 8B bf16 store. msq := 1 in dist (unit rows).
__global__ void mbnorm_kernel(const float* __restrict__ mb,
                              __bf16* __restrict__ mbbf) {
    int tid = blockIdx.x * 256 + threadIdx.x;
    int row = tid >> 4, sub = tid & 15;
    const float4 v = *(const float4*)(mb + (size_t)row * 64 + sub * 4);
    float ss = v.x * v.x + v.y * v.y + v.z * v.z + v.w * v.w;
#pragma unroll
    for (int o = 1; o < 16; o <<= 1) ss += __shfl_xor(ss, o, 64);
    float inv = 1.f / fmaxf(sqrtf(ss), 1e-12f);
    v4bf o;
    o[0] = (__bf16)(v.x * inv);
    o[1] = (__bf16)(v.y * inv);
    o[2] = (__bf16)(v.z * inv);
    o[3] = (__bf16)(v.w * inv);
    *(v4bf*)(mbbf + (size_t)row * 64 + sub * 4) = o;
}

// ---------------------------------------------------------------------------
// dist v18 = v14 (banked best: 331.7-332.1us, MfmaUtil ~80% of the 264.9us
// 16x16-pipe floor). Structural ceiling of the 2-barrier K-loop: R3/R6/R7
// proved more residency spills (~112-reg live set), R8 proved the in-lane-
// fold swap issues worse (70.7%), 32x32 MFMA infeasible (LDS-BW or tmax
// register wall). Remaining ~20% = barrier drain + wave skew at ~3.3 avg
// resident blocks/CU.
__global__ __launch_bounds__(256, 4)
void dist_kernel(const __bf16* __restrict__ q, const float* __restrict__ qsq,
                 const __bf16* __restrict__ mb,
                 unsigned int* __restrict__ mind2) {
    __shared__ __align__(16) __bf16 Bs[2][CHUNK * 64];   // 2 x 16 KB
    const int t = threadIdx.x;
    const int wave = t >> 6, lane = t & 63;
    const int c16 = lane & 15;        // m-col within tile / q-row for A
    const int kblk = lane >> 4;       // 0..3: k-subblock
    const int mbase = blockIdx.x * 256 + wave * 64;
    const int slice = blockIdx.y;

    // A fragments: 4 strips x 2 ksteps (32 VGPR).
    v8bf a[4][2];
#pragma unroll
    for (int s = 0; s < 4; ++s)
#pragma unroll
        for (int ks = 0; ks < 2; ++ks)
            a[s][ks] = *(const v8bf*)(q + (size_t)(mbase + s * 16 + c16) * 64
                                        + ks * 32 + kblk * 8);

    float tmax[4][4];
#pragma unroll
    for (int s = 0; s < 4; ++s)
#pragma unroll
        for (int r = 0; r < 4; ++r) tmax[s][r] = -3.0e38f;

    v4f Z;                            // hoisted zero C-operand (4 regs)
#pragma unroll
    for (int r = 0; r < 4; ++r) Z[r] = 0.f;

    // staging: granule g=j*256+t -> row g>>3, slot (g&7)^(row&7); granule j
    // at LDS offset j*4096 (j*32 ≡ 0 mod 8 -> swizzle j-invariant).
    const int r0 = t >> 3, c0 = (t & 7) ^ (r0 & 7);
    const __bf16* gp = mb + (size_t)slice * SLICE_LEN * 64 + r0 * 64 + c0 * 8;
    const int wbase = wave * 1024;

    // prologue: chunk 0 -> buf 0 (4 granules of 4KB)
#pragma unroll
    for (int j = 0; j < 4; ++j) {
        gload_lds16(gp, (char*)Bs[0] + j * 4096 + wbase);
        gp += 2048;
    }

    // ds_read offsets: data k-slot κ = kblk + 4*ks lives at physical slot
    // κ ^ (row&7); row = c16 -> byte = c16*128 + ((κ ^ (lane&7))<<4).
    const int rowb = c16 * 128;
    int offk[2];
#pragma unroll
    for (int ks = 0; ks < 2; ++ks) offk[ks] = (((kblk + 4 * ks) ^ (lane & 7)) << 4);

    auto step = [&](const char* bp, char* pdst, bool more) {
        __syncthreads();              // drains staging (vmcnt0) + sync
        if (more) {
#pragma unroll
            for (int j = 0; j < 4; ++j) {
                gload_lds16(gp, pdst + j * 4096 + wbase);
                gp += 2048;
            }
        }
        const char* tp = bp + rowb;
        v8bf be[2], bo[2];
#pragma unroll
        for (int ks = 0; ks < 2; ++ks) {
            be[ks] = *(const v8bf*)(tp + offk[ks]);           // m-tile 0
            bo[ks] = *(const v8bf*)(tp + 2048 + offk[ks]);    // m-tile 1
        }
#pragma unroll 1
        for (int p = 0; p < 4; ++p) {
            v4f Ae[4], Ao[4];
            // ks0: 8 independent chain heads
#pragma unroll
            for (int s = 0; s < 4; ++s)
                Ae[s] = __builtin_amdgcn_mfma_f32_16x16x32_bf16(a[s][0], be[0], Z, 0, 0, 0);
#pragma unroll
            for (int s = 0; s < 4; ++s)
                Ao[s] = __builtin_amdgcn_mfma_f32_16x16x32_bf16(a[s][0], bo[0], Z, 0, 0, 0);
            // ks1: finish the chains (dep gap = 8 issues)
#pragma unroll
            for (int s = 0; s < 4; ++s)
                Ae[s] = __builtin_amdgcn_mfma_f32_16x16x32_bf16(a[s][1], be[1], Ae[s], 0, 0, 0);
#pragma unroll
            for (int s = 0; s < 4; ++s)
                Ao[s] = __builtin_amdgcn_mfma_f32_16x16x32_bf16(a[s][1], bo[1], Ao[s], 0, 0, 0);
            // reload be/bo in place for the next pair (WAR safe: in-order issue)
            if (p < 3) {
                const char* tn = tp + (p + 1) * 4096;
#pragma unroll
                for (int ks = 0; ks < 2; ++ks) {
                    be[ks] = *(const v8bf*)(tn + offk[ks]);
                    bo[ks] = *(const v8bf*)(tn + 2048 + offk[ks]);
                }
            }
            // fold both m-tiles: fmax(fmax(.,.),.) -> v_max3_f32
#pragma unroll
            for (int s = 0; s < 4; ++s)
#pragma unroll
                for (int r = 0; r < 4; ++r)
                    tmax[s][r] = fmaxf(fmaxf(Ae[s][r], Ao[s][r]), tmax[s][r]);
        }
    };

    for (int ch = 0; ch < NCHUNKS; ch += 2) {
        step((const char*)Bs[0], (char*)Bs[1], ch + 1 < NCHUNKS);
        step((const char*)Bs[1], (char*)Bs[0], ch + 2 < NCHUNKS);
    }

    // cross-lane max over the 16 m-cols (lanes sharing lane>>4)
#pragma unroll
    for (int s = 0; s < 4; ++s)
#pragma unroll
        for (int r = 0; r < 4; ++r) {
            float v = tmax[s][r];
            v = fmaxf(v, __shfl_xor(v, 1, 64));
            v = fmaxf(v, __shfl_xor(v, 2, 64));
            v = fmaxf(v, __shfl_xor(v, 4, 64));
            v = fmaxf(v, __shfl_xor(v, 8, 64));
            tmax[s][r] = v;
        }
    if (c16 == 0) {
#pragma unroll
        for (int s = 0; s < 4; ++s)
#pragma unroll
            for (int r = 0; r < 4; ++r) {
                int m = mbase + s * 16 + kblk * 4 + r;  // C/D row map
                // d^2 = qsq + |m|^2 - 2 dot, |m|^2 := 1 (unit rows)
                float dd = fmaxf(qsq[m] + 1.0f - 2.0f * tmax[s][r], 0.f);
                atomicMin(mind2 + m, __float_as_uint(dd));
            }
    }
}

// finalize: out[b] = max_p sqrt(mind2[b*64+p])
__global__ void finalize_kernel(const unsigned int* __restrict__ mind2,
                                float* __restrict__ out) {
    int b = blockIdx.x, l = threadIdx.x;
    float v = __uint_as_float(mind2[b * 64 + l]);
    float d = sqrtf(fmaxf(v, 0.f));
#pragma unroll
    for (int o = 1; o < 64; o <<= 1) d = fmaxf(d, __shfl_xor(d, o, 64));
    if (l == 0) out[b] = d;
}

// ---------------------------------------------------------------------------
extern "C" void kernel_launch(void* const* d_in, const int* in_sizes, int n_in,
                              void* d_out, int out_size, void* d_ws, size_t ws_size,
                              hipStream_t stream) {
    (void)in_sizes; (void)n_in; (void)out_size; (void)ws_size;
    const float* x     = (const float*)d_in[0];
    const float* mbank = (const float*)d_in[1];
    const float* w0 = (const float*)d_in[2],  *b0 = (const float*)d_in[3];
    const float* g0 = (const float*)d_in[4],  *be0 = (const float*)d_in[5];
    const float* mn0 = (const float*)d_in[6], *vr0 = (const float*)d_in[7];
    const float* w1 = (const float*)d_in[8],  *b1 = (const float*)d_in[9];
    const float* g1 = (const float*)d_in[10], *be1 = (const float*)d_in[11];
    const float* mn1 = (const float*)d_in[12], *vr1 = (const float*)d_in[13];
    const float* w2 = (const float*)d_in[14], *b2 = (const float*)d_in[15];
    const float* g2 = (const float*)d_in[16], *be2 = (const float*)d_in[17];
    const float* mn2 = (const float*)d_in[18], *vr2 = (const float*)d_in[19];

    char* ws = (char*)d_ws;
    float*        y0    = (float*)(ws + 0);              // 16.78 MB
    float*        y1    = (float*)(ws + 16777216);       // 8.39 MB
    float*        y2    = (float*)(ws + 25165824);       // 4.19 MB
    __bf16*       qbf   = (__bf16*)(ws + 29360128);      // 2.10 MB
    float*        qsq   = (float*)(ws + 31457280);       // 64 KB
    __bf16*       mbbf  = (__bf16*)(ws + 31522816);      // 33.55 MB
    unsigned int* mind2 = (unsigned int*)(ws + 66125824);// 64 KB

    conv0_kernel<<<16384, 256, 0, stream>>>(x, w0, b0, g0, be0, mn0, vr0, y0);
    conv1_kernel<<<1024, 256, 0, stream>>>(y0, w1, b1, g1, be1, mn1, vr1, y1);
    conv2_kernel<<<1024, 256, 0, stream>>>(y1, w2, b2, g2, be2, mn2, vr2, y2);
    qnorm_kernel<<<256, 256, 0, stream>>>(y2, qbf, qsq, mind2);
    mbnorm_kernel<<<16384, 256, 0, stream>>>(mbank, mbbf);
    dist_kernel<<<dim3(64, SLICES), 256, 0, stream>>>(qbf, qsq, mbbf, mind2);
    finalize_kernel<<<256, 64, 0, stream>>>(mind2, (float*)d_out);
}